// Round 10
// baseline (2706.075 us; speedup 1.0000x reference)
//
#include <hip/hip_runtime.h>
#include <math.h>

#define L_SEQ 1024
#define WIN   32
#define CDIM  144
#define NW    993            // (1024-32)/1 + 1
#define HDIM  512
#define RDIM  256
#define M_ROWS (NW*CDIM)     // 142992
#define TILE_M 16
#define NBLK  (M_ROWS/TILE_M) // 8937
#define LP    17             // padded LDS row stride (conflict-free stores)
#define SLOPE 0.1

typedef double dx4 __attribute__((ext_vector_type(4)));

__device__ __forceinline__ double dlrelu(double x){ return x >= 0.0 ? x : SLOPE*x; }

// ---------------- prologue: axis-angle -> 6D (fp64 math) ----------------
__global__ void k_prep(const float* __restrict__ dp, float* __restrict__ d6){
  int idx = blockIdx.x*256 + threadIdx.x;
  if (idx >= L_SEQ*24) return;
  int l = idx / 24, j = idx % 24;
  const float* a = dp + l*72 + j*3;
  double x = (double)a[0], y = (double)a[1], z = (double)a[2];
  double ang = sqrt(x*x + y*y + z*z);
  double inv = 1.0 / fmax(ang, 1e-8);
  double ax = x*inv, ay = y*inv, az = z*inv;
  double s = sin(ang), c = cos(ang), C = 1.0 - c;
  float* o = d6 + l*CDIM + j*6;
  o[0] = (float)(c + ax*ax*C);
  o[1] = (float)(ax*ay*C - az*s);
  o[2] = (float)(ax*az*C + ay*s);
  o[3] = (float)(ay*ax*C + az*s);
  o[4] = (float)(c + ay*ay*C);
  o[5] = (float)(ay*az*C - ax*s);
}

// ------- fused weight prep: all transposes to k-major fp32, one launch ------
__global__ void k_wprep(const float* __restrict__ w_in, const float* __restrict__ w1a,
                        const float* __restrict__ w1b, const float* __restrict__ w2a,
                        const float* __restrict__ w2b, const float* __restrict__ w_out,
                        float* __restrict__ winT, float* __restrict__ w1aT,
                        float* __restrict__ w1bT, float* __restrict__ w2aT,
                        float* __restrict__ w2bT, float* __restrict__ woutT){
  int idx = blockIdx.x*256 + threadIdx.x;
  if (idx < 16384){                                   // w_in (512,32)
    int j = idx >> 5, k = idx & 31;
    winT[k*512 + j] = w_in[idx];
  } else if (idx < 147456){                           // w1a (256,512)
    int t = idx - 16384; int j = t >> 9, k = t & 511;
    w1aT[k*256 + j] = w1a[t];
  } else if (idx < 278528){                           // w1b (512,256)
    int t = idx - 147456; int j = t >> 8, k = t & 255;
    w1bT[k*512 + j] = w1b[t];
  } else if (idx < 409600){                           // w2a (256,512)
    int t = idx - 278528; int j = t >> 9, k = t & 511;
    w2aT[k*256 + j] = w2a[t];
  } else if (idx < 540672){                           // w2b (512,256)
    int t = idx - 409600; int j = t >> 8, k = t & 255;
    w2bT[k*512 + j] = w2b[t];
  } else if (idx < 557056){                           // w_out (32,512) -> [k][t]
    int t = idx - 540672; int j = t >> 9, k = t & 511;
    woutT[k*32 + j] = w_out[t];
  }
}

// ---------------- fused MLP via fp64 MFMA (8 waves / 512 threads) ----------
// Activations fp32 in LDS, layout [k][r] with padded stride LP=17 (store
// pattern j*LP+r is conflict-free: 17j mod 32 distinct for 16 lanes).
// Weights fp32 k-major in ws (L2-resident, 2.2 MB total). v_mfma_f64_16x16x4:
//   A: lane(row=l&15, k=l>>4);  B: lane(col=l&15, k=l>>4);
//   D: col=l&15, row=4*(l>>4)+i  (verified by R8 pass).
// fp64 accumulation; activations rounded through fp32 at each store; residual
// adds in fp32 — chains identical to R8 (absmax must stay 0.0625).
template<int KD, int JD, bool RES>
__device__ __forceinline__ void layer_mfma(const float* S, float* Dst,
                                           const float* __restrict__ Wt,
                                           const float* __restrict__ bias,
                                           int wave, int lr, int lk){
  constexpr int NT = JD / 128;         // col-tiles (16 cols each) per wave (8 waves)
  dx4 acc[NT];
  #pragma unroll
  for (int t = 0; t < NT; ++t) acc[t] = (dx4){0.0, 0.0, 0.0, 0.0};

  const int colbase = wave * (NT*16);
  for (int k0 = 0; k0 < KD; k0 += 4){
    double a = (double)S[(k0 + lk)*LP + lr];
    const float* wrow = Wt + (size_t)(k0 + lk)*JD + colbase + lr;
    #pragma unroll
    for (int t = 0; t < NT; ++t){
      double b = (double)wrow[t*16];
      acc[t] = __builtin_amdgcn_mfma_f64_16x16x4f64(a, b, acc[t], 0, 0, 0);
    }
  }

  #pragma unroll
  for (int t = 0; t < NT; ++t){
    int j = colbase + t*16 + lr;
    double bj = (double)bias[j];
    #pragma unroll
    for (int i = 0; i < 4; ++i){
      int r = 4*lk + i;
      float v = (float)dlrelu(acc[t][i] + bj);
      float* dp = Dst + j*LP + r;
      if (RES) *dp = *dp + v;          // fp32 residual add (reference chain)
      else     *dp = v;
    }
  }
}

__global__ __launch_bounds__(512, 6) void k_mlp(
    const float* __restrict__ d6,
    const float* __restrict__ winT, const float* __restrict__ b_in,
    const float* __restrict__ w1aT, const float* __restrict__ b1a,
    const float* __restrict__ w1bT, const float* __restrict__ b1b,
    const float* __restrict__ w2aT, const float* __restrict__ b2a,
    const float* __restrict__ w2bT, const float* __restrict__ b2b,
    const float* __restrict__ woutT, const float* __restrict__ b_out,
    float* __restrict__ y)
{
  __shared__ __align__(16) float hb[HDIM*LP];   // 34.8 KiB, [k][r] padded
  __shared__ __align__(16) float rb[RDIM*LP];   // 17.4 KiB; xb + L_out partials overlay
  const int tid  = threadIdx.x;
  const int wave = tid >> 6;           // 0..7
  const int lane = tid & 63;
  const int lr   = lane & 15;          // A-row / B-col / D-col
  const int lk   = lane >> 4;          // k within 4 / D row-group
  const int m0   = blockIdx.x * TILE_M;

  // gather input windows into xb (= rb): xb[t*LP + r] = d6[(n+t)*144 + c]
  if (tid < WIN*16){
    int r = tid & 15, t = tid >> 4;
    int m = m0 + r;
    int n = m / CDIM, c = m % CDIM;
    rb[t*LP + r] = d6[(n+t)*CDIM + c];
  }
  __syncthreads();

  layer_mfma<WIN , HDIM, false>(rb, hb, winT, b_in, wave, lr, lk); __syncthreads();
  layer_mfma<HDIM, RDIM, false>(hb, rb, w1aT, b1a, wave, lr, lk); __syncthreads();
  layer_mfma<RDIM, HDIM, true >(rb, hb, w1bT, b1b, wave, lr, lk); __syncthreads();
  layer_mfma<HDIM, RDIM, false>(hb, rb, w2aT, b2a, wave, lr, lk); __syncthreads();
  layer_mfma<RDIM, HDIM, true >(rb, hb, w2bT, b2b, wave, lr, lk); __syncthreads();

  // ---- L_out: 512 -> 32, k-split over waves 0-3 + fp64 LDS reduction ----
  {
    double* part = (double*)rb;        // 4 waves x 2 tiles x 256 = 2048 doubles (16 KB)
    if (wave < 4){
      dx4 acc0 = (dx4){0.0,0.0,0.0,0.0};
      dx4 acc1 = (dx4){0.0,0.0,0.0,0.0};
      const int kbase = wave * 128;
      for (int k0 = kbase; k0 < kbase + 128; k0 += 4){
        double a = (double)hb[(k0 + lk)*LP + lr];
        const float* wrow = woutT + (size_t)(k0 + lk)*32 + lr;
        acc0 = __builtin_amdgcn_mfma_f64_16x16x4f64(a, (double)wrow[0],  acc0, 0,0,0);
        acc1 = __builtin_amdgcn_mfma_f64_16x16x4f64(a, (double)wrow[16], acc1, 0,0,0);
      }
      #pragma unroll
      for (int i = 0; i < 4; ++i){
        part[wave*512 +   0 + (4*lk + i)*16 + lr] = acc0[i];
        part[wave*512 + 256 + (4*lk + i)*16 + lr] = acc1[i];
      }
    }
    __syncthreads();
    {
      int j = tid >> 4, r = tid & 15;  // 512 threads -> all 32x16 outputs
      int off = (j >> 4)*256 + r*16 + (j & 15);
      double s = (part[off] + part[512 + off]) + (part[1024 + off] + part[1536 + off]);
      int m = m0 + r;
      int n = m / CDIM, c = m % CDIM;
      y[(size_t)j*M_ROWS + n*CDIM + c] = (float)(s + (double)b_out[j]);
    }
  }
}

// ---------------- overlap-average scatter (fp64 sum) ----------------
__global__ void k_scatter(const float* __restrict__ y, float* __restrict__ seq){
  int idx = blockIdx.x*256 + threadIdx.x;
  if (idx >= L_SEQ*CDIM) return;
  int t = idx / CDIM, c = idx % CDIM;
  int nlo = t - (WIN-1); if (nlo < 0) nlo = 0;
  int nhi = t; if (nhi > NW-1) nhi = NW-1;
  double s = 0.0;
  for (int n = nlo; n <= nhi; ++n)
    s += (double)y[(size_t)(t-n)*M_ROWS + n*CDIM + c];
  seq[idx] = (float)(s / (double)(nhi - nlo + 1));
}

// ---------------- epilogue: 6D -> axis-angle (fp64 math) ----------------
__global__ void k_post(const float* __restrict__ seq, float* __restrict__ out){
  int idx = blockIdx.x*256 + threadIdx.x;
  if (idx >= L_SEQ*24) return;
  int t = idx / 24, j = idx % 24;
  const float* s = seq + t*CDIM + j*6;
  double a1x=(double)s[0], a1y=(double)s[1], a1z=(double)s[2];
  double a2x=(double)s[3], a2y=(double)s[4], a2z=(double)s[5];
  double n1 = sqrt(a1x*a1x + a1y*a1y + a1z*a1z);
  double i1 = 1.0 / fmax(n1, 1e-8);
  double b1x=a1x*i1, b1y=a1y*i1, b1z=a1z*i1;
  double d  = b1x*a2x + b1y*a2y + b1z*a2z;
  double px = a2x - d*b1x, py = a2y - d*b1y, pz = a2z - d*b1z;
  double n2 = sqrt(px*px + py*py + pz*pz);
  double i2 = 1.0 / fmax(n2, 1e-8);
  double b2x=px*i2, b2y=py*i2, b2z=pz*i2;
  double b3x = b1y*b2z - b1z*b2y;
  double b3y = b1z*b2x - b1x*b2z;
  double b3z = b1x*b2y - b1y*b2x;
  double tr = b1x + b2y + b3z;
  double cs = fmin(fmax((tr-1.0)*0.5, -1.0+1e-6), 1.0-1e-6);
  double ang = acos(cs);
  double sn  = sqrt(fmax(1.0 - cs*cs, 1e-12));
  double vx = b3y - b2z, vy = b1z - b3x, vz = b2x - b1y;
  double f = ang / (2.0 * sn);
  float* o = out + t*72 + j*3;
  o[0] = (float)(vx*f); o[1] = (float)(vy*f); o[2] = (float)(vz*f);
}

// ---------------- launcher ----------------
extern "C" void kernel_launch(void* const* d_in, const int* in_sizes, int n_in,
                              void* d_out, int out_size, void* d_ws, size_t ws_size,
                              hipStream_t stream) {
  const float* dp    = (const float*)d_in[0];
  const float* w_in  = (const float*)d_in[1];
  const float* b_in  = (const float*)d_in[2];
  const float* w1a   = (const float*)d_in[3];
  const float* b1a   = (const float*)d_in[4];
  const float* w1b   = (const float*)d_in[5];
  const float* b1b   = (const float*)d_in[6];
  const float* w2a   = (const float*)d_in[7];
  const float* b2a   = (const float*)d_in[8];
  const float* w2b   = (const float*)d_in[9];
  const float* b2b   = (const float*)d_in[10];
  const float* w_out = (const float*)d_in[11];
  const float* b_out = (const float*)d_in[12];
  float* out = (float*)d_out;

  float* d6    = (float*)d_ws;             // 1024*144            = 147456
  float* winT  = d6    + 147456;           // 32*512              = 16384
  float* w1aT  = winT  + 16384;            // 512*256             = 131072
  float* w1bT  = w1aT  + 131072;           // 256*512             = 131072
  float* w2aT  = w1bT  + 131072;
  float* w2bT  = w2aT  + 131072;
  float* woutT = w2bT  + 131072;           // 512*32              = 16384
  float* ybuf  = woutT + 16384;            // 32*993*144          = 4575744
  float* seq   = ybuf  + (size_t)WIN*NW*CDIM; // 147456

  k_prep<<<(L_SEQ*24 + 255)/256, 256, 0, stream>>>(dp, d6);

  k_wprep<<<(557056 + 255)/256, 256, 0, stream>>>(w_in, w1a, w1b, w2a, w2b, w_out,
                                                  winT, w1aT, w1bT, w2aT, w2bT, woutT);

  k_mlp<<<NBLK, 512, 0, stream>>>(d6,
      winT, b_in, w1aT, b1a, w1bT, b1b, w2aT, b2a, w2bT, b2b, woutT, b_out,
      ybuf);

  k_scatter<<<(L_SEQ*CDIM + 255)/256, 256, 0, stream>>>(ybuf, seq);
  k_post<<<(L_SEQ*24 + 255)/256, 256, 0, stream>>>(seq, out);
}

// Round 11
// 2656.606 us; speedup vs baseline: 1.0186x; 1.0186x over previous
//
#include <hip/hip_runtime.h>
#include <math.h>

#define L_SEQ 1024
#define WIN   32
#define CDIM  144
#define NW    993            // (1024-32)/1 + 1
#define HDIM  512
#define RDIM  256
#define M_ROWS (NW*CDIM)     // 142992
#define TILE_M 16
#define NBLK  (M_ROWS/TILE_M) // 8937
#define LP    17             // padded LDS row stride (conflict-free stores)
#define SLOPE 0.1

typedef double dx4 __attribute__((ext_vector_type(4)));
typedef float  fx4 __attribute__((ext_vector_type(4)));

__device__ __forceinline__ double dlrelu(double x){ return x >= 0.0 ? x : SLOPE*x; }

// ---------------- prologue: axis-angle -> 6D (fp64 math) ----------------
__global__ void k_prep(const float* __restrict__ dp, float* __restrict__ d6){
  int idx = blockIdx.x*256 + threadIdx.x;
  if (idx >= L_SEQ*24) return;
  int l = idx / 24, j = idx % 24;
  const float* a = dp + l*72 + j*3;
  double x = (double)a[0], y = (double)a[1], z = (double)a[2];
  double ang = sqrt(x*x + y*y + z*z);
  double inv = 1.0 / fmax(ang, 1e-8);
  double ax = x*inv, ay = y*inv, az = z*inv;
  double s = sin(ang), c = cos(ang), C = 1.0 - c;
  float* o = d6 + l*CDIM + j*6;
  o[0] = (float)(c + ax*ax*C);
  o[1] = (float)(ax*ay*C - az*s);
  o[2] = (float)(ax*az*C + ay*s);
  o[3] = (float)(ay*ax*C + az*s);
  o[4] = (float)(c + ay*ay*C);
  o[5] = (float)(ay*az*C - ax*s);
}

// ------- weight prep: k-chunk-16 layout, within-chunk permuted -------------
// Wq[(k>>4)*J*16 + j*16 + (k&3)*4 + ((k>>2)&3)] = W[j][k]   (W row-major J x K)
// A lane (col=j, lk) then loads ONE float4 per 16-k chunk at j*16 + lk*4,
// whose element s is the b-operand for MFMA step s (k = k0 + 4s + lk).
// Wave access = 16 consecutive 64B lines (1KB contiguous, zero over-fetch).
__global__ void k_wprep(const float* __restrict__ w_in, const float* __restrict__ w1a,
                        const float* __restrict__ w1b, const float* __restrict__ w2a,
                        const float* __restrict__ w2b, const float* __restrict__ w_out,
                        float* __restrict__ winQ, float* __restrict__ w1aQ,
                        float* __restrict__ w1bQ, float* __restrict__ w2aQ,
                        float* __restrict__ w2bQ, float* __restrict__ woutQ){
  int idx = blockIdx.x*256 + threadIdx.x;
  if (idx < 16384){                                   // w_in (512,32)
    int j = idx >> 5, k = idx & 31;
    winQ[(k>>4)*8192 + j*16 + (k&3)*4 + ((k>>2)&3)] = w_in[idx];
  } else if (idx < 147456){                           // w1a (256,512)
    int t = idx - 16384; int j = t >> 9, k = t & 511;
    w1aQ[(k>>4)*4096 + j*16 + (k&3)*4 + ((k>>2)&3)] = w1a[t];
  } else if (idx < 278528){                           // w1b (512,256)
    int t = idx - 147456; int j = t >> 8, k = t & 255;
    w1bQ[(k>>4)*8192 + j*16 + (k&3)*4 + ((k>>2)&3)] = w1b[t];
  } else if (idx < 409600){                           // w2a (256,512)
    int t = idx - 278528; int j = t >> 9, k = t & 511;
    w2aQ[(k>>4)*4096 + j*16 + (k&3)*4 + ((k>>2)&3)] = w2a[t];
  } else if (idx < 540672){                           // w2b (512,256)
    int t = idx - 409600; int j = t >> 8, k = t & 255;
    w2bQ[(k>>4)*8192 + j*16 + (k&3)*4 + ((k>>2)&3)] = w2b[t];
  } else if (idx < 557056){                           // w_out (32,512)
    int t = idx - 540672; int j = t >> 9, k = t & 511;
    woutQ[(k>>4)*512 + j*16 + (k&3)*4 + ((k>>2)&3)] = w_out[t];
  }
}

// ---------------- fused MLP via fp64 MFMA (8 waves / 512 threads) ----------
// Activations fp32 in LDS, [k][r] stride LP=17 (conflict-free stores, 2-way
// reads). Weights in chunked Wq layout: per 16-k chunk, per col-tile, ONE
// coalesced float4 load per lane. v_mfma_f64_16x16x4 (layout verified R8):
//   A: lane(row=l&15, k=l>>4); B: lane(col=l&15, k=l>>4); D: col=l&15,
//   row=4*(l>>4)+i. MFMA k-order identical to R8/R10 -> bit-identical output.
template<int KD, int JD, bool RES>
__device__ __forceinline__ void layer_mfma(const float* S, float* Dst,
                                           const float* __restrict__ Wq,
                                           const float* __restrict__ bias,
                                           int wave, int lr, int lk){
  constexpr int NT = JD / 128;         // col-tiles (16 cols each) per wave (8 waves)
  dx4 acc[NT];
  #pragma unroll
  for (int t = 0; t < NT; ++t) acc[t] = (dx4){0.0, 0.0, 0.0, 0.0};

  const int colbase = wave * (NT*16);
  const float* wbase = Wq + (size_t)(colbase + lr)*16 + lk*4;

  for (int k0 = 0; k0 < KD; k0 += 16){
    fx4 q[NT];
    #pragma unroll
    for (int t = 0; t < NT; ++t)
      q[t] = *(const fx4*)(wbase + (size_t)(k0>>4)*(JD*16) + t*256);
    #pragma unroll
    for (int s = 0; s < 4; ++s){
      double a = (double)S[(k0 + 4*s + lk)*LP + lr];
      #pragma unroll
      for (int t = 0; t < NT; ++t)
        acc[t] = __builtin_amdgcn_mfma_f64_16x16x4f64(a, (double)q[t][s], acc[t], 0, 0, 0);
    }
  }

  #pragma unroll
  for (int t = 0; t < NT; ++t){
    int j = colbase + t*16 + lr;
    double bj = (double)bias[j];
    #pragma unroll
    for (int i = 0; i < 4; ++i){
      int r = 4*lk + i;
      float v = (float)dlrelu(acc[t][i] + bj);
      float* dp = Dst + j*LP + r;
      if (RES) *dp = *dp + v;          // fp32 residual add (reference chain)
      else     *dp = v;
    }
  }
}

__global__ __launch_bounds__(512, 6) void k_mlp(
    const float* __restrict__ d6,
    const float* __restrict__ winQ, const float* __restrict__ b_in,
    const float* __restrict__ w1aQ, const float* __restrict__ b1a,
    const float* __restrict__ w1bQ, const float* __restrict__ b1b,
    const float* __restrict__ w2aQ, const float* __restrict__ b2a,
    const float* __restrict__ w2bQ, const float* __restrict__ b2b,
    const float* __restrict__ woutQ, const float* __restrict__ b_out,
    float* __restrict__ y)
{
  __shared__ __align__(16) float hb[HDIM*LP];   // 34.8 KiB, [k][r] padded
  __shared__ __align__(16) float rb[RDIM*LP];   // 17.4 KiB; xb + L_out partials overlay
  const int tid  = threadIdx.x;
  const int wave = tid >> 6;           // 0..7
  const int lane = tid & 63;
  const int lr   = lane & 15;          // A-row / B-col / D-col
  const int lk   = lane >> 4;          // k within 4 / D row-group
  const int m0   = blockIdx.x * TILE_M;

  // gather input windows into xb (= rb): xb[t*LP + r] = d6[(n+t)*144 + c]
  if (tid < WIN*16){
    int r = tid & 15, t = tid >> 4;
    int m = m0 + r;
    int n = m / CDIM, c = m % CDIM;
    rb[t*LP + r] = d6[(n+t)*CDIM + c];
  }
  __syncthreads();

  layer_mfma<WIN , HDIM, false>(rb, hb, winQ, b_in, wave, lr, lk); __syncthreads();
  layer_mfma<HDIM, RDIM, false>(hb, rb, w1aQ, b1a, wave, lr, lk); __syncthreads();
  layer_mfma<RDIM, HDIM, true >(rb, hb, w1bQ, b1b, wave, lr, lk); __syncthreads();
  layer_mfma<HDIM, RDIM, false>(hb, rb, w2aQ, b2a, wave, lr, lk); __syncthreads();
  layer_mfma<RDIM, HDIM, true >(rb, hb, w2bQ, b2b, wave, lr, lk); __syncthreads();

  // ---- L_out: 512 -> 32, k-split over waves 0-3 + fp64 LDS reduction ----
  {
    double* part = (double*)rb;        // 4 waves x 2 tiles x 256 = 2048 doubles (16 KB)
    if (wave < 4){
      dx4 acc0 = (dx4){0.0,0.0,0.0,0.0};
      dx4 acc1 = (dx4){0.0,0.0,0.0,0.0};
      const int kbase = wave * 128;
      for (int k0 = kbase; k0 < kbase + 128; k0 += 16){
        fx4 q0 = *(const fx4*)(woutQ + (size_t)(k0>>4)*512 + (lr     )*16 + lk*4);
        fx4 q1 = *(const fx4*)(woutQ + (size_t)(k0>>4)*512 + (lr + 16)*16 + lk*4);
        #pragma unroll
        for (int s = 0; s < 4; ++s){
          double a = (double)hb[(k0 + 4*s + lk)*LP + lr];
          acc0 = __builtin_amdgcn_mfma_f64_16x16x4f64(a, (double)q0[s], acc0, 0,0,0);
          acc1 = __builtin_amdgcn_mfma_f64_16x16x4f64(a, (double)q1[s], acc1, 0,0,0);
        }
      }
      #pragma unroll
      for (int i = 0; i < 4; ++i){
        part[wave*512 +   0 + (4*lk + i)*16 + lr] = acc0[i];
        part[wave*512 + 256 + (4*lk + i)*16 + lr] = acc1[i];
      }
    }
    __syncthreads();
    {
      int j = tid >> 4, r = tid & 15;  // 512 threads -> all 32x16 outputs
      int off = (j >> 4)*256 + r*16 + (j & 15);
      double s = (part[off] + part[512 + off]) + (part[1024 + off] + part[1536 + off]);
      int m = m0 + r;
      int n = m / CDIM, c = m % CDIM;
      y[(size_t)j*M_ROWS + n*CDIM + c] = (float)(s + (double)b_out[j]);
    }
  }
}

// ---------------- overlap-average scatter (fp64 sum) ----------------
__global__ void k_scatter(const float* __restrict__ y, float* __restrict__ seq){
  int idx = blockIdx.x*256 + threadIdx.x;
  if (idx >= L_SEQ*CDIM) return;
  int t = idx / CDIM, c = idx % CDIM;
  int nlo = t - (WIN-1); if (nlo < 0) nlo = 0;
  int nhi = t; if (nhi > NW-1) nhi = NW-1;
  double s = 0.0;
  for (int n = nlo; n <= nhi; ++n)
    s += (double)y[(size_t)(t-n)*M_ROWS + n*CDIM + c];
  seq[idx] = (float)(s / (double)(nhi - nlo + 1));
}

// ---------------- epilogue: 6D -> axis-angle (fp64 math) ----------------
__global__ void k_post(const float* __restrict__ seq, float* __restrict__ out){
  int idx = blockIdx.x*256 + threadIdx.x;
  if (idx >= L_SEQ*24) return;
  int t = idx / 24, j = idx % 24;
  const float* s = seq + t*CDIM + j*6;
  double a1x=(double)s[0], a1y=(double)s[1], a1z=(double)s[2];
  double a2x=(double)s[3], a2y=(double)s[4], a2z=(double)s[5];
  double n1 = sqrt(a1x*a1x + a1y*a1y + a1z*a1z);
  double i1 = 1.0 / fmax(n1, 1e-8);
  double b1x=a1x*i1, b1y=a1y*i1, b1z=a1z*i1;
  double d  = b1x*a2x + b1y*a2y + b1z*a2z;
  double px = a2x - d*b1x, py = a2y - d*b1y, pz = a2z - d*b1z;
  double n2 = sqrt(px*px + py*py + pz*pz);
  double i2 = 1.0 / fmax(n2, 1e-8);
  double b2x=px*i2, b2y=py*i2, b2z=pz*i2;
  double b3x = b1y*b2z - b1z*b2y;
  double b3y = b1z*b2x - b1x*b2z;
  double b3z = b1x*b2y - b1y*b2x;
  double tr = b1x + b2y + b3z;
  double cs = fmin(fmax((tr-1.0)*0.5, -1.0+1e-6), 1.0-1e-6);
  double ang = acos(cs);
  double sn  = sqrt(fmax(1.0 - cs*cs, 1e-12));
  double vx = b3y - b2z, vy = b1z - b3x, vz = b2x - b1y;
  double f = ang / (2.0 * sn);
  float* o = out + t*72 + j*3;
  o[0] = (float)(vx*f); o[1] = (float)(vy*f); o[2] = (float)(vz*f);
}

// ---------------- launcher ----------------
extern "C" void kernel_launch(void* const* d_in, const int* in_sizes, int n_in,
                              void* d_out, int out_size, void* d_ws, size_t ws_size,
                              hipStream_t stream) {
  const float* dp    = (const float*)d_in[0];
  const float* w_in  = (const float*)d_in[1];
  const float* b_in  = (const float*)d_in[2];
  const float* w1a   = (const float*)d_in[3];
  const float* b1a   = (const float*)d_in[4];
  const float* w1b   = (const float*)d_in[5];
  const float* b1b   = (const float*)d_in[6];
  const float* w2a   = (const float*)d_in[7];
  const float* b2a   = (const float*)d_in[8];
  const float* w2b   = (const float*)d_in[9];
  const float* b2b   = (const float*)d_in[10];
  const float* w_out = (const float*)d_in[11];
  const float* b_out = (const float*)d_in[12];
  float* out = (float*)d_out;

  float* d6    = (float*)d_ws;             // 1024*144            = 147456
  float* winQ  = d6    + 147456;           // 32*512              = 16384
  float* w1aQ  = winQ  + 16384;            // 512*256             = 131072
  float* w1bQ  = w1aQ  + 131072;           // 256*512             = 131072
  float* w2aQ  = w1bQ  + 131072;
  float* w2bQ  = w2aQ  + 131072;
  float* woutQ = w2bQ  + 131072;           // 512*32              = 16384
  float* ybuf  = woutQ + 16384;            // 32*993*144          = 4575744
  float* seq   = ybuf  + (size_t)WIN*NW*CDIM; // 147456

  k_prep<<<(L_SEQ*24 + 255)/256, 256, 0, stream>>>(dp, d6);

  k_wprep<<<(557056 + 255)/256, 256, 0, stream>>>(w_in, w1a, w1b, w2a, w2b, w_out,
                                                  winQ, w1aQ, w1bQ, w2aQ, w2bQ, woutQ);

  k_mlp<<<NBLK, 512, 0, stream>>>(d6,
      winQ, b_in, w1aQ, b1a, w1bQ, b1b, w2aQ, b2a, w2bQ, b2b, woutQ, b_out,
      ybuf);

  k_scatter<<<(L_SEQ*CDIM + 255)/256, 256, 0, stream>>>(ybuf, seq);
  k_post<<<(L_SEQ*24 + 255)/256, 256, 0, stream>>>(seq, out);
}